// Round 14
// baseline (6025.463 us; speedup 1.0000x reference)
//
#include <hip/hip_runtime.h>

// ---------------------------------------------------------------------------
// Problem constants
// ---------------------------------------------------------------------------
static constexpr int LSEQ = 512;   // timesteps
static constexpr int NB   = 256;   // batch
static constexpr int CIN  = 256;   // input dim
static constexpr int HD   = 512;   // hidden dim
static constexpr int G3   = 1536;  // 3*HD
static constexpr int NOUT = 256;   // output dim

typedef __attribute__((ext_vector_type(8))) short bf16x8;
typedef __attribute__((ext_vector_type(4))) float f32x4;
typedef __attribute__((ext_vector_type(8))) unsigned short u16x8;
typedef __attribute__((ext_vector_type(4))) unsigned u32x4;

#define DEVI __device__ __forceinline__

DEVI float b2f(unsigned short h) { return __uint_as_float(((unsigned)h) << 16); }
DEVI unsigned short f2b(float x) {
    unsigned u = __float_as_uint(x);
    return (unsigned short)((u + 0x7FFFu + ((u >> 16) & 1u)) >> 16);
}

// LLC-coherent (cross-XCD safe) dword access — THE validated flavor.
DEVI unsigned cload(const unsigned* p) {
    return __hip_atomic_load(p, __ATOMIC_RELAXED, __HIP_MEMORY_SCOPE_AGENT);
}
DEVI void cstore(unsigned* p, unsigned v) {
    __hip_atomic_store(p, v, __ATOMIC_RELAXED, __HIP_MEMORY_SCOPE_AGENT);
}
// Poll probe: asm load + vmcnt(0) (drains the wave's VMEM each probe).
DEVI unsigned cld_poll(const unsigned* p) {
    unsigned r;
    asm volatile("global_load_dword %0, %1, off sc0 sc1\n\ts_waitcnt vmcnt(0)"
                 : "=v"(r) : "v"(p) : "memory");
    return r;
}

// exp-based tanh: no libm branches.
DEVI float fast_tanh(float x) {
    x = fminf(10.f, fmaxf(-10.f, x));
    float e = __expf(-2.f * x);
    return (1.f - e) / (1.f + e);
}

// 4x coherent 16B loads (LLC), one waitcnt. sched_barrier guards against the
// compiler hoisting register-only consumers past the inline-asm waitcnt.
DEVI void cload4x4(const unsigned* p0, const unsigned* p1,
                   const unsigned* p2, const unsigned* p3,
                   u32x4& r0, u32x4& r1, u32x4& r2, u32x4& r3) {
    asm volatile(
        "global_load_dwordx4 %0, %4, off sc0 sc1\n\t"
        "global_load_dwordx4 %1, %5, off sc0 sc1\n\t"
        "global_load_dwordx4 %2, %6, off sc0 sc1\n\t"
        "global_load_dwordx4 %3, %7, off sc0 sc1\n\t"
        "s_waitcnt vmcnt(0)"
        : "=&v"(r0), "=&v"(r1), "=&v"(r2), "=&v"(r3)
        : "v"(p0), "v"(p1), "v"(p2), "v"(p3)
        : "memory");
    __builtin_amdgcn_sched_barrier(0);
}

// ---------------------------------------------------------------------------
// Float-dtype detection (f32 vs bf16 harness data).
// ---------------------------------------------------------------------------
__global__ void detect_fdt(const unsigned short* __restrict__ x, int nHalf,
                           unsigned* __restrict__ fdt) {
    __shared__ unsigned big;
    if (threadIdx.x == 0) big = 0;
    __syncthreads();
    for (int i = threadIdx.x; i < nHalf; i += 256) {
        unsigned e = (x[i] >> 7) & 0xFFu;
        if (e >= 0xC0u) atomicOr(&big, 1u);
    }
    __syncthreads();
    if (threadIdx.x == 0) *fdt = big ? 1u : 0u;
}

__global__ void cast_bf16(const void* __restrict__ src, long srcOff,
                          unsigned short* __restrict__ dst, long n,
                          const unsigned* __restrict__ fdt) {
    long i = (long)blockIdx.x * 256 + threadIdx.x;
    long stride = (long)gridDim.x * 256;
    if (*fdt) {
        const float* s = (const float*)src + srcOff;
        for (; i < n; i += stride) dst[i] = f2b(s[i]);
    } else {
        const unsigned short* s = (const unsigned short*)src + srcOff;
        for (; i < n; i += stride) dst[i] = s[i];
    }
}

__global__ void detect_done(const unsigned char* __restrict__ d, int elems,
                            unsigned* __restrict__ flag) {
    __shared__ unsigned bad[4];
    int tid = threadIdx.x;
    if (tid < 4) bad[tid] = 0;
    __syncthreads();
    int nInt = elems >> 2;
    const unsigned* di = (const unsigned*)d;
    for (int i = tid; i < nInt; i += 256) {
        unsigned v = di[i];
        if (v > 1u) atomicOr(&bad[0], 1u);
        if (v != 0u && v != 0x3F800000u) atomicOr(&bad[1], 1u);
    }
    int nHalf = elems >> 1;
    const unsigned short* dh = (const unsigned short*)d;
    for (int i = tid; i < nHalf; i += 256) {
        unsigned short h = dh[i];
        if (h != 0 && h != 0x3F80) atomicOr(&bad[2], 1u);
    }
    __syncthreads();
    if (tid == 0) {
        unsigned f;
        if (!bad[0]) f = 0u;       // int32 0/1
        else if (!bad[1]) f = 3u;  // float32
        else if (!bad[2]) f = 2u;  // bf16
        else f = 1u;               // bytes (bool / int8)
        *flag = f;
    }
}

__global__ void expand_done(const void* __restrict__ d, const unsigned* __restrict__ flag,
                            float* __restrict__ keep, int elems) {
    int i = blockIdx.x * 256 + threadIdx.x;
    if (i >= elems) return;
    unsigned f = *flag;
    float v;
    if (f == 0u)      v = (float)((const int*)d)[i];
    else if (f == 1u) v = (float)((const unsigned char*)d)[i];
    else if (f == 2u) v = b2f(((const unsigned short*)d)[i]);
    else              v = ((const float*)d)[i];
    keep[i] = 1.f - v;
}

// ---------------------------------------------------------------------------
// NT GEMM: C[M,N] = A[M,K] @ B[N,K]^T + bias, bf16 in, f32 accum.
// ---------------------------------------------------------------------------
__global__ __launch_bounds__(256) void gemm_nt(
    const unsigned short* __restrict__ A, const unsigned short* __restrict__ B,
    const unsigned short* __restrict__ bias, unsigned short* __restrict__ C,
    float* __restrict__ Cf, const unsigned* __restrict__ fdt,
    int M, int N, int K) {
    __shared__ unsigned short sm[16384];  // A: [0,8192), B: [8192,16384)
    const int tid = threadIdx.x;
    const int l = tid & 63, w = tid >> 6;
    const int lr = l & 15, lq = l >> 4;
    const int wr = w >> 1, wc = w & 1;
    const long rowBase = (long)blockIdx.y * 128;
    const long colBase = (long)blockIdx.x * 128;

    int qrow[4], qc8[4];
#pragma unroll
    for (int i = 0; i < 4; i++) {
        int q = (i * 4 + w) * 64 + l;
        qrow[i] = q >> 3;
        qc8[i] = (q & 7) * 8;
    }

    f32x4 acc[4][4] = {};

    for (int k0 = 0; k0 < K; k0 += 64) {
#pragma unroll
        for (int i = 0; i < 4; i++) {
            const unsigned short* sA = A + (rowBase + qrow[i]) * K + k0 + qc8[i];
            const unsigned short* sB = B + (colBase + qrow[i]) * K + k0 + qc8[i];
            __builtin_amdgcn_global_load_lds(
                (const __attribute__((address_space(1))) void*)sA,
                (__attribute__((address_space(3))) void*)(sm + (i * 4 + w) * 512), 16, 0, 0);
            __builtin_amdgcn_global_load_lds(
                (const __attribute__((address_space(1))) void*)sB,
                (__attribute__((address_space(3))) void*)(sm + 8192 + (i * 4 + w) * 512), 16, 0, 0);
        }
        __syncthreads();
#pragma unroll
        for (int ks = 0; ks < 2; ks++) {
            bf16x8 af[4], bfr[4];
#pragma unroll
            for (int mi = 0; mi < 4; mi++)
                af[mi] = *(const bf16x8*)&sm[(wr * 64 + mi * 16 + lr) * 64 + ks * 32 + lq * 8];
#pragma unroll
            for (int ni = 0; ni < 4; ni++)
                bfr[ni] = *(const bf16x8*)&sm[8192 + (wc * 64 + ni * 16 + lr) * 64 + ks * 32 + lq * 8];
#pragma unroll
            for (int mi = 0; mi < 4; mi++)
#pragma unroll
                for (int ni = 0; ni < 4; ni++)
                    acc[mi][ni] = __builtin_amdgcn_mfma_f32_16x16x32_bf16(
                        af[mi], bfr[ni], acc[mi][ni], 0, 0, 0);
        }
        __syncthreads();
    }

    float bv[4];
#pragma unroll
    for (int ni = 0; ni < 4; ni++)
        bv[ni] = bias ? b2f(bias[colBase + wc * 64 + ni * 16 + lr]) : 0.f;

    const bool f32out = (fdt != nullptr) && (*fdt != 0u);
    if (f32out) {
#pragma unroll
        for (int mi = 0; mi < 4; mi++)
#pragma unroll
            for (int ni = 0; ni < 4; ni++)
#pragma unroll
                for (int rg = 0; rg < 4; rg++) {
                    int m = wr * 64 + mi * 16 + lq * 4 + rg;
                    int n = wc * 64 + ni * 16 + lr;
                    Cf[(rowBase + m) * (long)N + colBase + n] = acc[mi][ni][rg] + bv[ni];
                }
        return;
    }

#pragma unroll
    for (int mi = 0; mi < 4; mi++)
#pragma unroll
        for (int ni = 0; ni < 4; ni++)
#pragma unroll
            for (int rg = 0; rg < 4; rg++) {
                int m = wr * 64 + mi * 16 + lq * 4 + rg;
                int n = wc * 64 + ni * 16 + lr;
                sm[m * 128 + n] = f2b(acc[mi][ni][rg] + bv[ni]);
            }
    __syncthreads();
#pragma unroll
    for (int i = 0; i < 8; i++) {
        int idx = i * 2048 + tid * 8;
        int r = idx >> 7, c = idx & 127;
        *(u16x8*)(C + (rowBase + r) * N + colBase + c) = *(const u16x8*)&sm[idx];
    }
}

// ---------------------------------------------------------------------------
// GRU recurrence — round-13 base (PASSED, 296us/dispatch) with ONE composite
// delta: PER-WAVE barrier. Each wave's h-stores cover complete batch rows
// (wave w stores rows 4w..4w+3, all its cols), so consumers need "all 64
// waves posted", not "all 16 blocks". Arrive: per-wave vmcnt(0) drain ->
// lane0 posts wave-flag (64 flags/line). Wait: all-wave poll (lane l reads
// flag l, __all). No trailing __syncthreads (each wave has its own proof);
// the red-LDS WAR across steps is fixed by parity double-buffering
// red[2][..]. ONE __syncthreads per step (was 3 + thread0 relay).
// Sync-epoch safety: a wave reaches step k only after all waves posted
// line k, which happens after their step-(k-1) sync -> all waves always
// meet at the same iteration's barrier.
// ---------------------------------------------------------------------------
__global__ __launch_bounds__(256, 1) void gru_rec(
    const unsigned short* __restrict__ gi,   // [Tc][NB][G3] bf16 (bih folded in)
    const unsigned short* __restrict__ Whh,  // [G3][HD] bf16 (staged)
    const unsigned short* __restrict__ bhh,  // [G3] bf16 (staged)
    const float* __restrict__ keep,          // [LSEQ][NB]
    const unsigned short* __restrict__ mem,  // [NB][1024] bf16 (staged)
    unsigned short* __restrict__ hdb,        // [2][NB][HD] double buffer
    unsigned short* __restrict__ Y,          // [Tc][NB][HD] chunk-local bf16
    unsigned short* __restrict__ hnB,        // [NB][1024] bf16 out
    float* __restrict__ hnF,                 // [NB][1024] f32 out
    const unsigned* __restrict__ fdt,
    int t0, int Tc, int layerOff,
    unsigned* __restrict__ ctr) {            // (Tc+2)*16 lines x 64 dwords
    const int tid = threadIdx.x;
    const int l = tid & 63, w = tid >> 6, lr = l & 15, lq = l >> 4;
    const int bi = blockIdx.x & 15, bj = blockIdx.x >> 4;
    const bool f32out = (*fdt != 0u);

    __shared__ float red[2][4][16][100];  // parity dbuf, padded stride (51 KB)

    // --- Whh fragments -> registers (one-time) ---
    bf16x8 wreg[6][4];
#pragma unroll
    for (int fr = 0; fr < 6; fr++) {
        int g = fr >> 1, cf = fr & 1;
        long row = (long)g * HD + bj * 32 + cf * 16 + lr;
#pragma unroll
        for (int ks = 0; ks < 4; ks++) {
            int k = w * 128 + ks * 32 + lq * 8;
            wreg[fr][ks] = *(const bf16x8*)(Whh + row * HD + k);
        }
    }

    const int m = tid >> 4, c0 = (tid & 15) * 2;
    const int n_g = bi * 16 + m;
    const int ch = bj * 32 + c0;
    float bh[3][2];
#pragma unroll
    for (int g = 0; g < 3; g++) {
        unsigned v = *(const unsigned*)(bhh + g * HD + ch);
        bh[g][0] = b2f((unsigned short)(v & 0xffffu));
        bh[g][1] = b2f((unsigned short)(v >> 16));
    }

    if (t0 == 0) {  // init h0 from memory into parity 0, per-wave barrier
        unsigned v = *(const unsigned*)(mem + (long)n_g * 1024 + layerOff + ch);
        cstore((unsigned*)(hdb + (long)n_g * HD + ch), v);
        unsigned* iline = ctr + ((long)(Tc + 1) * 16 + bi) * 64;
        asm volatile("s_waitcnt vmcnt(0)" ::: "memory");  // drain own init store
        if (l == 0) cstore(iline + bj * 4 + w, 1u);
        unsigned vv;
        do { vv = cld_poll(iline + l); } while (!__all(vv != 0u));
    }

    // own h pair carried in registers (bf16-rounded == what others read)
    float hpv[2];
    {
        unsigned hp0 = cload((const unsigned*)(hdb + (long)(t0 & 1) * NB * HD + (long)n_g * HD + ch));
        hpv[0] = b2f((unsigned short)(hp0 & 0xffffu));
        hpv[1] = b2f((unsigned short)(hp0 >> 16));
    }

    // prefetch gi/keep for first step
    unsigned gv[3];
    float kp;
    {
        const unsigned short* gp = gi + (long)n_g * G3;
#pragma unroll
        for (int g = 0; g < 3; g++) gv[g] = *(const unsigned*)(gp + g * HD + ch);
        kp = keep[(long)t0 * NB + n_g];
    }

    for (int t = t0; t < t0 + Tc; ++t) {
        const unsigned short* hc = hdb + (long)(t & 1) * NB * HD;
        unsigned short* hx = hdb + (long)((t + 1) & 1) * NB * HD;
        const int par = t & 1;

        // coherent 16B loads of the h stripe (written by other blocks' waves)
        const unsigned* hrow = (const unsigned*)(hc + (long)(bi * 16 + lr) * HD);
        union { u32x4 u; bf16x8 v; } t0u, t1u, t2u, t3u;
        cload4x4(hrow + w * 64 + 0 * 16 + lq * 4, hrow + w * 64 + 1 * 16 + lq * 4,
                 hrow + w * 64 + 2 * 16 + lq * 4, hrow + w * 64 + 3 * 16 + lq * 4,
                 t0u.u, t1u.u, t2u.u, t3u.u);
        bf16x8 af[4] = { t0u.v, t1u.v, t2u.v, t3u.v };

        f32x4 acc[6] = {};
#pragma unroll
        for (int ks = 0; ks < 4; ks++)
#pragma unroll
            for (int fr = 0; fr < 6; fr++)
                acc[fr] = __builtin_amdgcn_mfma_f32_16x16x32_bf16(af[ks], wreg[fr][ks], acc[fr], 0, 0, 0);

#pragma unroll
        for (int fr = 0; fr < 6; fr++)
#pragma unroll
            for (int rg = 0; rg < 4; rg++)
                red[par][w][lq * 4 + rg][fr * 16 + lr] = acc[fr][rg];
        __syncthreads();  // the ONLY sync per step

        float s[3][2];
#pragma unroll
        for (int g = 0; g < 3; g++) { s[g][0] = 0.f; s[g][1] = 0.f; }
#pragma unroll
        for (int ww = 0; ww < 4; ww++)
#pragma unroll
            for (int g = 0; g < 3; g++) {
                const float* p = &red[par][ww][m][g * 32 + c0];
                s[g][0] += p[0];
                s[g][1] += p[1];
            }

        unsigned short yo[2], ho[2];
        float hcf[2];
#pragma unroll
        for (int j = 0; j < 2; j++) {
            float ir  = b2f((unsigned short)((gv[0] >> (16 * j)) & 0xffffu));
            float iz  = b2f((unsigned short)((gv[1] >> (16 * j)) & 0xffffu));
            float in_ = b2f((unsigned short)((gv[2] >> (16 * j)) & 0xffffu));
            float r = 1.f / (1.f + __expf(-(ir + s[0][j] + bh[0][j])));
            float z = 1.f / (1.f + __expf(-(iz + s[1][j] + bh[1][j])));
            float nn = fast_tanh(in_ + r * (s[2][j] + bh[2][j]));
            float hnew = (1.f - z) * nn + z * hpv[j];
            hcf[j] = hnew * kp;
            yo[j] = f2b(hnew);
            ho[j] = f2b(hcf[j]);
            hpv[j] = b2f(ho[j]);  // carry bf16-rounded h*keep for next step
        }
        unsigned ypack = (unsigned)yo[0] | ((unsigned)yo[1] << 16);
        unsigned hpack = (unsigned)ho[0] | ((unsigned)ho[1] << 16);

        // barrier-gated h store first (atomic, compiler-visible)
        cstore((unsigned*)(hx + (long)n_g * HD + ch), hpack);

        const bool last = (t + 1 >= t0 + Tc);
        unsigned* line = ctr + ((long)(t - t0 + 1) * 16 + bi) * 64;
        if (!last) {
            // per-wave arrive: drain own wave's VMEM (h store), post wave flag
            asm volatile("s_waitcnt vmcnt(0)" ::: "memory");
            if (l == 0) cstore(line + bj * 4 + w, 1u);
        }

        // ---- non-barrier-gated work, overlapped with group arrival ----
        *(unsigned*)(Y + ((long)(t - t0) * NB + n_g) * HD + ch) = ypack;  // cross-kernel
        if (t == LSEQ - 1) {
            if (f32out) {
                hnF[(long)n_g * 1024 + layerOff + ch]     = hcf[0];
                hnF[(long)n_g * 1024 + layerOff + ch + 1] = hcf[1];
            } else {
                *(unsigned*)(hnB + (long)n_g * 1024 + layerOff + ch) = hpack;
            }
        }
        if (!last) {
            // prefetch next step's gi/keep (independent of h) under the poll
            const unsigned short* gp = gi + ((long)(t + 1 - t0) * NB + n_g) * G3;
#pragma unroll
            for (int g = 0; g < 3; g++) gv[g] = *(const unsigned*)(gp + g * HD + ch);
            kp = keep[(long)(t + 1) * NB + n_g];
            // all-wave wait: 64 wave-flags, lane l polls flag l
            unsigned v;
            do { v = cld_poll(line + l); } while (!__all(v != 0u));
        }
    }
}

// ---------------------------------------------------------------------------
// Host launcher — dtype-adaptive chunked two-layer pipeline.
// ---------------------------------------------------------------------------
extern "C" void kernel_launch(void* const* d_in, const int* in_sizes, int n_in,
                              void* d_out, int out_size, void* d_ws, size_t ws_size,
                              hipStream_t stream) {
    const void* x    = d_in[0];
    const void* mem  = d_in[1];
    const void* done = d_in[2];
    const void* fsrc[11] = { mem, d_in[3], d_in[4], d_in[5], d_in[6],
                             d_in[7], d_in[8], d_in[9], d_in[10], d_in[11], d_in[12] };
    const long  fn[11]   = { (long)NB * 1024, (long)G3 * CIN, (long)G3 * HD, G3, G3,
                             (long)G3 * HD, (long)G3 * HD, G3, G3, (long)NOUT * HD, NOUT };

    unsigned short* outB = (unsigned short*)d_out;
    float*          outF = (float*)d_out;
    unsigned short* hnB  = outB + (size_t)LSEQ * NB * NOUT;
    float*          hnF  = outF + (size_t)LSEQ * NB * NOUT;

    char* ws = (char*)d_ws;
    const size_t oFlag = 0;                                   // fdt @ +0, done-flag @ +64
    const size_t oKeep = 256;
    const size_t oCtr  = oKeep + (size_t)LSEQ * NB * 4;       // 8 MB barrier flag lines
    const size_t oWC   = oCtr + (size_t)8 * 1024 * 1024;      // staged weights/mem
    size_t wcTot = 0;
    size_t wcOff[11];
    for (int i = 0; i < 11; i++) { wcOff[i] = wcTot; wcTot += (size_t)fn[i] * 2; wcTot = (wcTot + 255) & ~(size_t)255; }
    const size_t oHdb0 = oWC + wcTot;
    const size_t oHdb1 = oHdb0 + (size_t)2 * NB * HD * 2;
    const size_t oDyn  = oHdb1 + (size_t)2 * NB * HD * 2;

    int Tc = 4;
    const int cand[6] = {128, 64, 32, 16, 8, 4};
    for (int i = 0; i < 6; i++) {
        size_t need = oDyn + (size_t)cand[i] * NB * (CIN + G3 + 2 * HD) * 2;
        if (need <= ws_size) { Tc = cand[i]; break; }
    }
    const size_t oXC  = oDyn;
    const size_t oGI  = oXC + (size_t)Tc * NB * CIN * 2;
    const size_t oY0c = oGI + (size_t)Tc * NB * G3 * 2;
    const size_t oY1c = oY0c + (size_t)Tc * NB * HD * 2;

    unsigned*       FDT  = (unsigned*)(ws + oFlag);
    unsigned*       DFLG = (unsigned*)(ws + oFlag + 64);
    float*          KEEP = (float*)(ws + oKeep);
    unsigned*       CTR  = (unsigned*)(ws + oCtr);
    unsigned short* WC   = (unsigned short*)(ws + oWC);
    unsigned short* HDB0 = (unsigned short*)(ws + oHdb0);
    unsigned short* HDB1 = (unsigned short*)(ws + oHdb1);
    unsigned short* XC   = (unsigned short*)(ws + oXC);
    unsigned short* GIb  = (unsigned short*)(ws + oGI);
    unsigned short* Y0c  = (unsigned short*)(ws + oY0c);
    unsigned short* Y1c  = (unsigned short*)(ws + oY1c);

    unsigned short* MEMc = WC + wcOff[0] / 2;
    unsigned short* WIH0 = WC + wcOff[1] / 2;
    unsigned short* WHH0 = WC + wcOff[2] / 2;
    unsigned short* BIH0 = WC + wcOff[3] / 2;
    unsigned short* BHH0 = WC + wcOff[4] / 2;
    unsigned short* WIH1 = WC + wcOff[5] / 2;
    unsigned short* WHH1 = WC + wcOff[6] / 2;
    unsigned short* BIH1 = WC + wcOff[7] / 2;
    unsigned short* BHH1 = WC + wcOff[8] / 2;
    unsigned short* WPc  = WC + wcOff[9] / 2;
    unsigned short* BPc  = WC + wcOff[10] / 2;

    hipMemsetAsync(ws + oCtr, 0, (size_t)8 * 1024 * 1024, stream);
    detect_fdt<<<1, 256, 0, stream>>>((const unsigned short*)x, 4096, FDT);
    detect_done<<<1, 256, 0, stream>>>((const unsigned char*)done, in_sizes[2], DFLG);
    expand_done<<<(LSEQ * NB + 255) / 256, 256, 0, stream>>>(done, DFLG, KEEP, LSEQ * NB);

    for (int i = 0; i < 11; i++) {
        int blocks = (int)((fn[i] + 1023) / 1024);
        if (blocks > 2048) blocks = 2048;
        cast_bf16<<<blocks, 256, 0, stream>>>(fsrc[i], 0, WC + wcOff[i] / 2, fn[i], FDT);
    }

    size_t ctrWords = 0;
    const size_t ctrStep = (size_t)(Tc + 2) * 16 * 64;  // lines x 64 dwords
    for (int t0 = 0; t0 < LSEQ; t0 += Tc) {
        const long xcN = (long)Tc * NB * CIN;
        cast_bf16<<<2048, 256, 0, stream>>>(x, (long)t0 * NB * CIN, XC, xcN, FDT);
        gemm_nt<<<dim3(G3 / 128, Tc * NB / 128), 256, 0, stream>>>(
            XC, WIH0, BIH0, GIb, nullptr, nullptr, Tc * NB, G3, CIN);
        gru_rec<<<256, 256, 0, stream>>>(GIb, WHH0, BHH0, KEEP, MEMc, HDB0,
                                         Y0c, hnB, hnF, FDT, t0, Tc, 0, CTR + ctrWords);
        ctrWords += ctrStep;
        gemm_nt<<<dim3(G3 / 128, Tc * NB / 128), 256, 0, stream>>>(
            Y0c, WIH1, BIH1, GIb, nullptr, nullptr, Tc * NB, G3, HD);
        gru_rec<<<256, 256, 0, stream>>>(GIb, WHH1, BHH1, KEEP, MEMc, HDB1,
                                         Y1c, hnB, hnF, FDT, t0, Tc, HD, CTR + ctrWords);
        ctrWords += ctrStep;
        gemm_nt<<<dim3(NOUT / 128, Tc * NB / 128), 256, 0, stream>>>(
            Y1c, WPc, BPc, outB + (size_t)t0 * NB * NOUT,
            outF + (size_t)t0 * NB * NOUT, FDT, Tc * NB, NOUT, HD);
    }
}

// Round 15
// 2447.972 us; speedup vs baseline: 2.4614x; 2.4614x over previous
//
#include <hip/hip_runtime.h>

// ---------------------------------------------------------------------------
// Problem constants
// ---------------------------------------------------------------------------
static constexpr int LSEQ = 512;   // timesteps
static constexpr int NB   = 256;   // batch
static constexpr int CIN  = 256;   // input dim
static constexpr int HD   = 512;   // hidden dim
static constexpr int G3   = 1536;  // 3*HD
static constexpr int NOUT = 256;   // output dim

typedef __attribute__((ext_vector_type(8))) short bf16x8;
typedef __attribute__((ext_vector_type(4))) float f32x4;
typedef __attribute__((ext_vector_type(8))) unsigned short u16x8;
typedef __attribute__((ext_vector_type(4))) unsigned u32x4;

#define DEVI __device__ __forceinline__

DEVI float b2f(unsigned short h) { return __uint_as_float(((unsigned)h) << 16); }
DEVI unsigned short f2b(float x) {
    unsigned u = __float_as_uint(x);
    return (unsigned short)((u + 0x7FFFu + ((u >> 16) & 1u)) >> 16);
}

// LLC-coherent (cross-XCD safe) dword access — THE validated flavor.
DEVI unsigned cload(const unsigned* p) {
    return __hip_atomic_load(p, __ATOMIC_RELAXED, __HIP_MEMORY_SCOPE_AGENT);
}
DEVI void cstore(unsigned* p, unsigned v) {
    __hip_atomic_store(p, v, __ATOMIC_RELAXED, __HIP_MEMORY_SCOPE_AGENT);
}

// exp-based tanh: no libm branches.
DEVI float fast_tanh(float x) {
    x = fminf(10.f, fmaxf(-10.f, x));
    float e = __expf(-2.f * x);
    return (1.f - e) / (1.f + e);
}

// 4x coherent 16B loads (LLC), one waitcnt. sched_barrier guards against the
// compiler hoisting register-only consumers past the inline-asm waitcnt.
DEVI void cload4x4(const unsigned* p0, const unsigned* p1,
                   const unsigned* p2, const unsigned* p3,
                   u32x4& r0, u32x4& r1, u32x4& r2, u32x4& r3) {
    asm volatile(
        "global_load_dwordx4 %0, %4, off sc0 sc1\n\t"
        "global_load_dwordx4 %1, %5, off sc0 sc1\n\t"
        "global_load_dwordx4 %2, %6, off sc0 sc1\n\t"
        "global_load_dwordx4 %3, %7, off sc0 sc1\n\t"
        "s_waitcnt vmcnt(0)"
        : "=&v"(r0), "=&v"(r1), "=&v"(r2), "=&v"(r3)
        : "v"(p0), "v"(p1), "v"(p2), "v"(p3)
        : "memory");
    __builtin_amdgcn_sched_barrier(0);
}

// ---------------------------------------------------------------------------
// Float-dtype detection (f32 vs bf16 harness data).
// ---------------------------------------------------------------------------
__global__ void detect_fdt(const unsigned short* __restrict__ x, int nHalf,
                           unsigned* __restrict__ fdt) {
    __shared__ unsigned big;
    if (threadIdx.x == 0) big = 0;
    __syncthreads();
    for (int i = threadIdx.x; i < nHalf; i += 256) {
        unsigned e = (x[i] >> 7) & 0xFFu;
        if (e >= 0xC0u) atomicOr(&big, 1u);
    }
    __syncthreads();
    if (threadIdx.x == 0) *fdt = big ? 1u : 0u;
}

__global__ void cast_bf16(const void* __restrict__ src, long srcOff,
                          unsigned short* __restrict__ dst, long n,
                          const unsigned* __restrict__ fdt) {
    long i = (long)blockIdx.x * 256 + threadIdx.x;
    long stride = (long)gridDim.x * 256;
    if (*fdt) {
        const float* s = (const float*)src + srcOff;
        for (; i < n; i += stride) dst[i] = f2b(s[i]);
    } else {
        const unsigned short* s = (const unsigned short*)src + srcOff;
        for (; i < n; i += stride) dst[i] = s[i];
    }
}

__global__ void detect_done(const unsigned char* __restrict__ d, int elems,
                            unsigned* __restrict__ flag) {
    __shared__ unsigned bad[4];
    int tid = threadIdx.x;
    if (tid < 4) bad[tid] = 0;
    __syncthreads();
    int nInt = elems >> 2;
    const unsigned* di = (const unsigned*)d;
    for (int i = tid; i < nInt; i += 256) {
        unsigned v = di[i];
        if (v > 1u) atomicOr(&bad[0], 1u);
        if (v != 0u && v != 0x3F800000u) atomicOr(&bad[1], 1u);
    }
    int nHalf = elems >> 1;
    const unsigned short* dh = (const unsigned short*)d;
    for (int i = tid; i < nHalf; i += 256) {
        unsigned short h = dh[i];
        if (h != 0 && h != 0x3F80) atomicOr(&bad[2], 1u);
    }
    __syncthreads();
    if (tid == 0) {
        unsigned f;
        if (!bad[0]) f = 0u;       // int32 0/1
        else if (!bad[1]) f = 3u;  // float32
        else if (!bad[2]) f = 2u;  // bf16
        else f = 1u;               // bytes (bool / int8)
        *flag = f;
    }
}

__global__ void expand_done(const void* __restrict__ d, const unsigned* __restrict__ flag,
                            float* __restrict__ keep, int elems) {
    int i = blockIdx.x * 256 + threadIdx.x;
    if (i >= elems) return;
    unsigned f = *flag;
    float v;
    if (f == 0u)      v = (float)((const int*)d)[i];
    else if (f == 1u) v = (float)((const unsigned char*)d)[i];
    else if (f == 2u) v = b2f(((const unsigned short*)d)[i]);
    else              v = ((const float*)d)[i];
    keep[i] = 1.f - v;
}

// ---------------------------------------------------------------------------
// NT GEMM: C[M,N] = A[M,K] @ B[N,K]^T + bias, bf16 in, f32 accum.
// ---------------------------------------------------------------------------
__global__ __launch_bounds__(256) void gemm_nt(
    const unsigned short* __restrict__ A, const unsigned short* __restrict__ B,
    const unsigned short* __restrict__ bias, unsigned short* __restrict__ C,
    float* __restrict__ Cf, const unsigned* __restrict__ fdt,
    int M, int N, int K) {
    __shared__ unsigned short sm[16384];  // A: [0,8192), B: [8192,16384)
    const int tid = threadIdx.x;
    const int l = tid & 63, w = tid >> 6;
    const int lr = l & 15, lq = l >> 4;
    const int wr = w >> 1, wc = w & 1;
    const long rowBase = (long)blockIdx.y * 128;
    const long colBase = (long)blockIdx.x * 128;

    int qrow[4], qc8[4];
#pragma unroll
    for (int i = 0; i < 4; i++) {
        int q = (i * 4 + w) * 64 + l;
        qrow[i] = q >> 3;
        qc8[i] = (q & 7) * 8;
    }

    f32x4 acc[4][4] = {};

    for (int k0 = 0; k0 < K; k0 += 64) {
#pragma unroll
        for (int i = 0; i < 4; i++) {
            const unsigned short* sA = A + (rowBase + qrow[i]) * K + k0 + qc8[i];
            const unsigned short* sB = B + (colBase + qrow[i]) * K + k0 + qc8[i];
            __builtin_amdgcn_global_load_lds(
                (const __attribute__((address_space(1))) void*)sA,
                (__attribute__((address_space(3))) void*)(sm + (i * 4 + w) * 512), 16, 0, 0);
            __builtin_amdgcn_global_load_lds(
                (const __attribute__((address_space(1))) void*)sB,
                (__attribute__((address_space(3))) void*)(sm + 8192 + (i * 4 + w) * 512), 16, 0, 0);
        }
        __syncthreads();
#pragma unroll
        for (int ks = 0; ks < 2; ks++) {
            bf16x8 af[4], bfr[4];
#pragma unroll
            for (int mi = 0; mi < 4; mi++)
                af[mi] = *(const bf16x8*)&sm[(wr * 64 + mi * 16 + lr) * 64 + ks * 32 + lq * 8];
#pragma unroll
            for (int ni = 0; ni < 4; ni++)
                bfr[ni] = *(const bf16x8*)&sm[8192 + (wc * 64 + ni * 16 + lr) * 64 + ks * 32 + lq * 8];
#pragma unroll
            for (int mi = 0; mi < 4; mi++)
#pragma unroll
                for (int ni = 0; ni < 4; ni++)
                    acc[mi][ni] = __builtin_amdgcn_mfma_f32_16x16x32_bf16(
                        af[mi], bfr[ni], acc[mi][ni], 0, 0, 0);
        }
        __syncthreads();
    }

    float bv[4];
#pragma unroll
    for (int ni = 0; ni < 4; ni++)
        bv[ni] = bias ? b2f(bias[colBase + wc * 64 + ni * 16 + lr]) : 0.f;

    const bool f32out = (fdt != nullptr) && (*fdt != 0u);
    if (f32out) {
#pragma unroll
        for (int mi = 0; mi < 4; mi++)
#pragma unroll
            for (int ni = 0; ni < 4; ni++)
#pragma unroll
                for (int rg = 0; rg < 4; rg++) {
                    int m = wr * 64 + mi * 16 + lq * 4 + rg;
                    int n = wc * 64 + ni * 16 + lr;
                    Cf[(rowBase + m) * (long)N + colBase + n] = acc[mi][ni][rg] + bv[ni];
                }
        return;
    }

#pragma unroll
    for (int mi = 0; mi < 4; mi++)
#pragma unroll
        for (int ni = 0; ni < 4; ni++)
#pragma unroll
            for (int rg = 0; rg < 4; rg++) {
                int m = wr * 64 + mi * 16 + lq * 4 + rg;
                int n = wc * 64 + ni * 16 + lr;
                sm[m * 128 + n] = f2b(acc[mi][ni][rg] + bv[ni]);
            }
    __syncthreads();
#pragma unroll
    for (int i = 0; i < 8; i++) {
        int idx = i * 2048 + tid * 8;
        int r = idx >> 7, c = idx & 127;
        *(u16x8*)(C + (rowBase + r) * N + colBase + c) = *(const u16x8*)&sm[idx];
    }
}

// ---------------------------------------------------------------------------
// GRU recurrence body — r13 kernel VERBATIM as a device function (passed,
// 296us/dispatch): split barrier (drain-sync -> thread0 fetch_add arrive ->
// overlapped Y/hn stores + gi prefetch -> thread0 spin -> sync).
// lb = local block id 0..255: bi = lb&15 (batch rows), bj = lb>>4 (32 cols).
// ---------------------------------------------------------------------------
DEVI void gru_body(
    const unsigned short* __restrict__ gi,   // [Tc][NB][G3]
    const unsigned short* __restrict__ Whh,  // [G3][HD]
    const unsigned short* __restrict__ bhh,  // [G3]
    const float* __restrict__ keep,          // [LSEQ][NB]
    const unsigned short* __restrict__ mem,  // [NB][1024]
    unsigned short* __restrict__ hdb,        // [2][NB][HD]
    unsigned short* __restrict__ Y,          // [Tc][NB][HD]
    unsigned short* __restrict__ hnB, float* __restrict__ hnF,
    bool f32out, int t0, int Tc, int layerOff,
    unsigned* __restrict__ ctr, int lb) {
    const int tid = threadIdx.x;
    const int l = tid & 63, w = tid >> 6, lr = l & 15, lq = l >> 4;
    const int bi = lb & 15, bj = lb >> 4;

    __shared__ float red[4][16][100];  // padded stride

    // --- Whh fragments -> registers (one-time) ---
    bf16x8 wreg[6][4];
#pragma unroll
    for (int fr = 0; fr < 6; fr++) {
        int g = fr >> 1, cf = fr & 1;
        long row = (long)g * HD + bj * 32 + cf * 16 + lr;
#pragma unroll
        for (int ks = 0; ks < 4; ks++) {
            int k = w * 128 + ks * 32 + lq * 8;
            wreg[fr][ks] = *(const bf16x8*)(Whh + row * HD + k);
        }
    }

    const int m = tid >> 4, c0 = (tid & 15) * 2;
    const int n_g = bi * 16 + m;
    const int ch = bj * 32 + c0;
    float bh[3][2];
#pragma unroll
    for (int g = 0; g < 3; g++) {
        unsigned v = *(const unsigned*)(bhh + g * HD + ch);
        bh[g][0] = b2f((unsigned short)(v & 0xffffu));
        bh[g][1] = b2f((unsigned short)(v >> 16));
    }

    if (t0 == 0) {  // init h0 from memory (layer slice) into parity 0
        unsigned v = *(const unsigned*)(mem + (long)n_g * 1024 + layerOff + ch);
        cstore((unsigned*)(hdb + (long)n_g * HD + ch), v);
        unsigned* islot = ctr + ((long)Tc * 16 + bi) * 32;
        __syncthreads();
        if (tid == 0) {
            __hip_atomic_fetch_add(islot, 1u, __ATOMIC_RELAXED, __HIP_MEMORY_SCOPE_AGENT);
            while (__hip_atomic_load(islot, __ATOMIC_RELAXED, __HIP_MEMORY_SCOPE_AGENT) < 16u)
                __builtin_amdgcn_s_sleep(1);
        }
        __syncthreads();
    }

    // own h pair carried in registers (bf16-rounded == what others read)
    float hpv[2];
    {
        unsigned hp0 = cload((const unsigned*)(hdb + (long)(t0 & 1) * NB * HD + (long)n_g * HD + ch));
        hpv[0] = b2f((unsigned short)(hp0 & 0xffffu));
        hpv[1] = b2f((unsigned short)(hp0 >> 16));
    }

    // prefetch gi/keep for first step
    unsigned gv[3];
    float kp;
    {
        const unsigned short* gp = gi + (long)n_g * G3;
#pragma unroll
        for (int g = 0; g < 3; g++) gv[g] = *(const unsigned*)(gp + g * HD + ch);
        kp = keep[(long)t0 * NB + n_g];
    }

    for (int t = t0; t < t0 + Tc; ++t) {
        const unsigned short* hc = hdb + (long)(t & 1) * NB * HD;
        unsigned short* hx = hdb + (long)((t + 1) & 1) * NB * HD;

        const unsigned* hrow = (const unsigned*)(hc + (long)(bi * 16 + lr) * HD);
        union { u32x4 u; bf16x8 v; } t0u, t1u, t2u, t3u;
        cload4x4(hrow + w * 64 + 0 * 16 + lq * 4, hrow + w * 64 + 1 * 16 + lq * 4,
                 hrow + w * 64 + 2 * 16 + lq * 4, hrow + w * 64 + 3 * 16 + lq * 4,
                 t0u.u, t1u.u, t2u.u, t3u.u);
        bf16x8 af[4] = { t0u.v, t1u.v, t2u.v, t3u.v };

        f32x4 acc[6] = {};
#pragma unroll
        for (int ks = 0; ks < 4; ks++)
#pragma unroll
            for (int fr = 0; fr < 6; fr++)
                acc[fr] = __builtin_amdgcn_mfma_f32_16x16x32_bf16(af[ks], wreg[fr][ks], acc[fr], 0, 0, 0);

#pragma unroll
        for (int fr = 0; fr < 6; fr++)
#pragma unroll
            for (int rg = 0; rg < 4; rg++)
                red[w][lq * 4 + rg][fr * 16 + lr] = acc[fr][rg];
        __syncthreads();

        float s[3][2];
#pragma unroll
        for (int g = 0; g < 3; g++) { s[g][0] = 0.f; s[g][1] = 0.f; }
#pragma unroll
        for (int ww = 0; ww < 4; ww++)
#pragma unroll
            for (int g = 0; g < 3; g++) {
                const float* p = &red[ww][m][g * 32 + c0];
                s[g][0] += p[0];
                s[g][1] += p[1];
            }

        unsigned short yo[2], ho[2];
        float hcf[2];
#pragma unroll
        for (int j = 0; j < 2; j++) {
            float ir  = b2f((unsigned short)((gv[0] >> (16 * j)) & 0xffffu));
            float iz  = b2f((unsigned short)((gv[1] >> (16 * j)) & 0xffffu));
            float in_ = b2f((unsigned short)((gv[2] >> (16 * j)) & 0xffffu));
            float r = 1.f / (1.f + __expf(-(ir + s[0][j] + bh[0][j])));
            float z = 1.f / (1.f + __expf(-(iz + s[1][j] + bh[1][j])));
            float nn = fast_tanh(in_ + r * (s[2][j] + bh[2][j]));
            float hnew = (1.f - z) * nn + z * hpv[j];
            hcf[j] = hnew * kp;
            yo[j] = f2b(hnew);
            ho[j] = f2b(hcf[j]);
            hpv[j] = b2f(ho[j]);
        }
        unsigned ypack = (unsigned)yo[0] | ((unsigned)yo[1] << 16);
        unsigned hpack = (unsigned)ho[0] | ((unsigned)ho[1] << 16);

        cstore((unsigned*)(hx + (long)n_g * HD + ch), hpack);  // barrier-gated

        const bool last = (t + 1 >= t0 + Tc);
        unsigned* slot = ctr + ((long)(t - t0) * 16 + bi) * 32;
        if (!last) {
            __syncthreads();  // drains the h cstore
            if (tid == 0)
                __hip_atomic_fetch_add(slot, 1u, __ATOMIC_RELAXED, __HIP_MEMORY_SCOPE_AGENT);
        }

        // non-barrier-gated work overlapped with group arrival
        *(unsigned*)(Y + ((long)(t - t0) * NB + n_g) * HD + ch) = ypack;
        if (t == LSEQ - 1) {
            if (f32out) {
                hnF[(long)n_g * 1024 + layerOff + ch]     = hcf[0];
                hnF[(long)n_g * 1024 + layerOff + ch + 1] = hcf[1];
            } else {
                *(unsigned*)(hnB + (long)n_g * 1024 + layerOff + ch) = hpack;
            }
        }
        if (!last) {
            const unsigned short* gp = gi + ((long)(t + 1 - t0) * NB + n_g) * G3;
#pragma unroll
            for (int g = 0; g < 3; g++) gv[g] = *(const unsigned*)(gp + g * HD + ch);
            kp = keep[(long)(t + 1) * NB + n_g];
            if (tid == 0) {
                while (__hip_atomic_load(slot, __ATOMIC_RELAXED, __HIP_MEMORY_SCOPE_AGENT) < 16u)
                    __builtin_amdgcn_s_sleep(1);
            }
            __syncthreads();
        }
    }
}

// ---------------------------------------------------------------------------
// Dual-layer dispatch: blocks 0-255 run layer A (L0 chunk c), blocks 256-511
// run layer B (L1 chunk c-1). The halves are fully independent (disjoint
// gi/hdb/Y/ctr; shared read-only keep/mem). 2 blocks/CU co-resident.
// ---------------------------------------------------------------------------
__global__ __launch_bounds__(256, 2) void gru_dual(
    const unsigned short* giA, const unsigned short* WhhA, const unsigned short* bhhA,
    unsigned short* hdbA, unsigned short* YA, int t0A, unsigned* ctrA, int enA,
    const unsigned short* giB, const unsigned short* WhhB, const unsigned short* bhhB,
    unsigned short* hdbB, unsigned short* YB, int t0B, unsigned* ctrB, int enB,
    const float* keep, const unsigned short* mem,
    unsigned short* hnB, float* hnF, const unsigned* fdt, int Tc) {
    const bool f32out = (*fdt != 0u);
    const int half = blockIdx.x >> 8;
    const int lb = blockIdx.x & 255;
    if (half == 0) {
        if (enA) gru_body(giA, WhhA, bhhA, keep, mem, hdbA, YA, hnB, hnF,
                          f32out, t0A, Tc, 0, ctrA, lb);
    } else {
        if (enB) gru_body(giB, WhhB, bhhB, keep, mem, hdbB, YB, hnB, hnF,
                          f32out, t0B, Tc, HD, ctrB, lb);
    }
}

// ---------------------------------------------------------------------------
// Host launcher — layer-pipelined: dual(L0 chunk c || L1 chunk c-1).
// ---------------------------------------------------------------------------
extern "C" void kernel_launch(void* const* d_in, const int* in_sizes, int n_in,
                              void* d_out, int out_size, void* d_ws, size_t ws_size,
                              hipStream_t stream) {
    const void* x    = d_in[0];
    const void* mem  = d_in[1];
    const void* done = d_in[2];
    const void* fsrc[11] = { mem, d_in[3], d_in[4], d_in[5], d_in[6],
                             d_in[7], d_in[8], d_in[9], d_in[10], d_in[11], d_in[12] };
    const long  fn[11]   = { (long)NB * 1024, (long)G3 * CIN, (long)G3 * HD, G3, G3,
                             (long)G3 * HD, (long)G3 * HD, G3, G3, (long)NOUT * HD, NOUT };

    unsigned short* outB = (unsigned short*)d_out;
    float*          outF = (float*)d_out;
    unsigned short* hnB  = outB + (size_t)LSEQ * NB * NOUT;
    float*          hnF  = outF + (size_t)LSEQ * NB * NOUT;

    char* ws = (char*)d_ws;
    const size_t oFlag = 0;                                   // fdt @ +0, done-flag @ +64
    const size_t oKeep = 256;
    const size_t oCtr  = oKeep + (size_t)LSEQ * NB * 4;       // 8 MB barrier slots
    const size_t oWC   = oCtr + (size_t)8 * 1024 * 1024;      // staged weights/mem
    size_t wcTot = 0;
    size_t wcOff[11];
    for (int i = 0; i < 11; i++) { wcOff[i] = wcTot; wcTot += (size_t)fn[i] * 2; wcTot = (wcTot + 255) & ~(size_t)255; }
    const size_t oHdb0 = oWC + wcTot;
    const size_t oHdb1 = oHdb0 + (size_t)2 * NB * HD * 2;
    const size_t oDyn  = oHdb1 + (size_t)2 * NB * HD * 2;

    int Tc = 4;
    const int cand[6] = {128, 64, 32, 16, 8, 4};
    for (int i = 0; i < 6; i++) {
        size_t need = oDyn + (size_t)cand[i] * NB * (CIN + 2 * G3 + 2 * HD) * 2;
        if (need <= ws_size) { Tc = cand[i]; break; }
    }
    const size_t oXC  = oDyn;
    const size_t oGI0 = oXC + (size_t)Tc * NB * CIN * 2;
    const size_t oGI1 = oGI0 + (size_t)Tc * NB * G3 * 2;
    const size_t oY0c = oGI1 + (size_t)Tc * NB * G3 * 2;
    const size_t oY1c = oY0c + (size_t)Tc * NB * HD * 2;

    unsigned*       FDT  = (unsigned*)(ws + oFlag);
    unsigned*       DFLG = (unsigned*)(ws + oFlag + 64);
    float*          KEEP = (float*)(ws + oKeep);
    unsigned*       CTR  = (unsigned*)(ws + oCtr);
    unsigned short* WC   = (unsigned short*)(ws + oWC);
    unsigned short* HDB0 = (unsigned short*)(ws + oHdb0);
    unsigned short* HDB1 = (unsigned short*)(ws + oHdb1);
    unsigned short* XC   = (unsigned short*)(ws + oXC);
    unsigned short* GI0  = (unsigned short*)(ws + oGI0);
    unsigned short* GI1  = (unsigned short*)(ws + oGI1);
    unsigned short* Y0c  = (unsigned short*)(ws + oY0c);
    unsigned short* Y1c  = (unsigned short*)(ws + oY1c);

    unsigned short* MEMc = WC + wcOff[0] / 2;
    unsigned short* WIH0 = WC + wcOff[1] / 2;
    unsigned short* WHH0 = WC + wcOff[2] / 2;
    unsigned short* BIH0 = WC + wcOff[3] / 2;
    unsigned short* BHH0 = WC + wcOff[4] / 2;
    unsigned short* WIH1 = WC + wcOff[5] / 2;
    unsigned short* WHH1 = WC + wcOff[6] / 2;
    unsigned short* BIH1 = WC + wcOff[7] / 2;
    unsigned short* BHH1 = WC + wcOff[8] / 2;
    unsigned short* WPc  = WC + wcOff[9] / 2;
    unsigned short* BPc  = WC + wcOff[10] / 2;

    hipMemsetAsync(ws + oCtr, 0, (size_t)8 * 1024 * 1024, stream);
    detect_fdt<<<1, 256, 0, stream>>>((const unsigned short*)x, 4096, FDT);
    detect_done<<<1, 256, 0, stream>>>((const unsigned char*)done, in_sizes[2], DFLG);
    expand_done<<<(LSEQ * NB + 255) / 256, 256, 0, stream>>>(done, DFLG, KEEP, LSEQ * NB);

    for (int i = 0; i < 11; i++) {
        int blocks = (int)((fn[i] + 1023) / 1024);
        if (blocks > 2048) blocks = 2048;
        cast_bf16<<<blocks, 256, 0, stream>>>(fsrc[i], 0, WC + wcOff[i] / 2, fn[i], FDT);
    }

    const int NC = LSEQ / Tc;
    const size_t SZ = (size_t)(Tc + 2) * 16 * 32;  // ctr region dwords per instance
    const long giN = (long)Tc * NB * CIN;

    // prologue: GI0 for chunk 0
    cast_bf16<<<2048, 256, 0, stream>>>(x, 0, XC, giN, FDT);
    gemm_nt<<<dim3(G3 / 128, Tc * NB / 128), 256, 0, stream>>>(
        XC, WIH0, BIH0, GI0, nullptr, nullptr, Tc * NB, G3, CIN);

    for (int it = 0; it <= NC; ++it) {
        const int cA = it, cB = it - 1;
        const int enA = (cA < NC) ? 1 : 0;
        const int enB = (cB >= 0) ? 1 : 0;

        gru_dual<<<512, 256, 0, stream>>>(
            GI0, WHH0, BHH0, HDB0, Y0c, cA * Tc, CTR + (size_t)(2 * it) * SZ, enA,
            GI1, WHH1, BHH1, HDB1, Y1c, cB * Tc, CTR + (size_t)(2 * it + 1) * SZ, enB,
            KEEP, MEMc, hnB, hnF, FDT, Tc);

        if (enA)  // GI1 for L1 chunk cA (consumed next iteration)
            gemm_nt<<<dim3(G3 / 128, Tc * NB / 128), 256, 0, stream>>>(
                Y0c, WIH1, BIH1, GI1, nullptr, nullptr, Tc * NB, G3, HD);
        if (enB)  // projection of L1 chunk cB
            gemm_nt<<<dim3(NOUT / 128, Tc * NB / 128), 256, 0, stream>>>(
                Y1c, WPc, BPc, outB + (size_t)cB * Tc * NB * NOUT,
                outF + (size_t)cB * Tc * NB * NOUT, FDT, Tc * NB, NOUT, HD);
        if (cA + 1 < NC) {  // GI0 for L0 chunk cA+1
            cast_bf16<<<2048, 256, 0, stream>>>(x, (long)(cA + 1) * Tc * NB * CIN, XC, giN, FDT);
            gemm_nt<<<dim3(G3 / 128, Tc * NB / 128), 256, 0, stream>>>(
                XC, WIH0, BIH0, GI0, nullptr, nullptr, Tc * NB, G3, CIN);
        }
    }
}

// Round 16
// 2436.800 us; speedup vs baseline: 2.4727x; 1.0046x over previous
//
#include <hip/hip_runtime.h>

// ---------------------------------------------------------------------------
// Problem constants
// ---------------------------------------------------------------------------
static constexpr int LSEQ = 512;   // timesteps
static constexpr int NB   = 256;   // batch
static constexpr int CIN  = 256;   // input dim
static constexpr int HD   = 512;   // hidden dim
static constexpr int G3   = 1536;  // 3*HD
static constexpr int NOUT = 256;   // output dim

typedef __attribute__((ext_vector_type(8))) short bf16x8;
typedef __attribute__((ext_vector_type(4))) float f32x4;
typedef __attribute__((ext_vector_type(8))) unsigned short u16x8;
typedef __attribute__((ext_vector_type(4))) unsigned u32x4;

#define DEVI __device__ __forceinline__

DEVI float b2f(unsigned short h) { return __uint_as_float(((unsigned)h) << 16); }
DEVI unsigned short f2b(float x) {
    unsigned u = __float_as_uint(x);
    return (unsigned short)((u + 0x7FFFu + ((u >> 16) & 1u)) >> 16);
}

// LLC-coherent (cross-XCD safe) dword access — THE validated flavor.
DEVI unsigned cload(const unsigned* p) {
    return __hip_atomic_load(p, __ATOMIC_RELAXED, __HIP_MEMORY_SCOPE_AGENT);
}
DEVI void cstore(unsigned* p, unsigned v) {
    __hip_atomic_store(p, v, __ATOMIC_RELAXED, __HIP_MEMORY_SCOPE_AGENT);
}

// exp-based tanh: no libm branches.
DEVI float fast_tanh(float x) {
    x = fminf(10.f, fmaxf(-10.f, x));
    float e = __expf(-2.f * x);
    return (1.f - e) / (1.f + e);
}

// 4x coherent 16B loads (LLC), one waitcnt. sched_barrier guards against the
// compiler hoisting register-only consumers past the inline-asm waitcnt.
DEVI void cload4x4(const unsigned* p0, const unsigned* p1,
                   const unsigned* p2, const unsigned* p3,
                   u32x4& r0, u32x4& r1, u32x4& r2, u32x4& r3) {
    asm volatile(
        "global_load_dwordx4 %0, %4, off sc0 sc1\n\t"
        "global_load_dwordx4 %1, %5, off sc0 sc1\n\t"
        "global_load_dwordx4 %2, %6, off sc0 sc1\n\t"
        "global_load_dwordx4 %3, %7, off sc0 sc1\n\t"
        "s_waitcnt vmcnt(0)"
        : "=&v"(r0), "=&v"(r1), "=&v"(r2), "=&v"(r3)
        : "v"(p0), "v"(p1), "v"(p2), "v"(p3)
        : "memory");
    __builtin_amdgcn_sched_barrier(0);
}

// ---------------------------------------------------------------------------
// Float-dtype detection (f32 vs bf16 harness data).
// ---------------------------------------------------------------------------
__global__ void detect_fdt(const unsigned short* __restrict__ x, int nHalf,
                           unsigned* __restrict__ fdt) {
    __shared__ unsigned big;
    if (threadIdx.x == 0) big = 0;
    __syncthreads();
    for (int i = threadIdx.x; i < nHalf; i += 256) {
        unsigned e = (x[i] >> 7) & 0xFFu;
        if (e >= 0xC0u) atomicOr(&big, 1u);
    }
    __syncthreads();
    if (threadIdx.x == 0) *fdt = big ? 1u : 0u;
}

__global__ void cast_bf16(const void* __restrict__ src, long srcOff,
                          unsigned short* __restrict__ dst, long n,
                          const unsigned* __restrict__ fdt) {
    long i = (long)blockIdx.x * 256 + threadIdx.x;
    long stride = (long)gridDim.x * 256;
    if (*fdt) {
        const float* s = (const float*)src + srcOff;
        for (; i < n; i += stride) dst[i] = f2b(s[i]);
    } else {
        const unsigned short* s = (const unsigned short*)src + srcOff;
        for (; i < n; i += stride) dst[i] = s[i];
    }
}

__global__ void detect_done(const unsigned char* __restrict__ d, int elems,
                            unsigned* __restrict__ flag) {
    __shared__ unsigned bad[4];
    int tid = threadIdx.x;
    if (tid < 4) bad[tid] = 0;
    __syncthreads();
    int nInt = elems >> 2;
    const unsigned* di = (const unsigned*)d;
    for (int i = tid; i < nInt; i += 256) {
        unsigned v = di[i];
        if (v > 1u) atomicOr(&bad[0], 1u);
        if (v != 0u && v != 0x3F800000u) atomicOr(&bad[1], 1u);
    }
    int nHalf = elems >> 1;
    const unsigned short* dh = (const unsigned short*)d;
    for (int i = tid; i < nHalf; i += 256) {
        unsigned short h = dh[i];
        if (h != 0 && h != 0x3F80) atomicOr(&bad[2], 1u);
    }
    __syncthreads();
    if (tid == 0) {
        unsigned f;
        if (!bad[0]) f = 0u;       // int32 0/1
        else if (!bad[1]) f = 3u;  // float32
        else if (!bad[2]) f = 2u;  // bf16
        else f = 1u;               // bytes (bool / int8)
        *flag = f;
    }
}

__global__ void expand_done(const void* __restrict__ d, const unsigned* __restrict__ flag,
                            float* __restrict__ keep, int elems) {
    int i = blockIdx.x * 256 + threadIdx.x;
    if (i >= elems) return;
    unsigned f = *flag;
    float v;
    if (f == 0u)      v = (float)((const int*)d)[i];
    else if (f == 1u) v = (float)((const unsigned char*)d)[i];
    else if (f == 2u) v = b2f(((const unsigned short*)d)[i]);
    else              v = ((const float*)d)[i];
    keep[i] = 1.f - v;
}

// ---------------------------------------------------------------------------
// GEMM tile body (m97-style, verbatim from the proven gemm_nt) as a device
// function: C[M,N] = A[M,K] @ B[N,K]^T + bias at tile (tx,ty).
// f32 output iff Cf != null AND *fdt (projection segment only).
// ---------------------------------------------------------------------------
DEVI void gemm_tile(
    const unsigned short* __restrict__ A, const unsigned short* __restrict__ B,
    const unsigned short* __restrict__ bias, unsigned short* __restrict__ C,
    float* __restrict__ Cf, const unsigned* __restrict__ fdt,
    int M, int N, int K, int tx, int ty, unsigned short* sm /*16384 shorts*/) {
    const int tid = threadIdx.x;
    const int l = tid & 63, w = tid >> 6;
    const int lr = l & 15, lq = l >> 4;
    const int wr = w >> 1, wc = w & 1;
    const long rowBase = (long)ty * 128;
    const long colBase = (long)tx * 128;

    int qrow[4], qc8[4];
#pragma unroll
    for (int i = 0; i < 4; i++) {
        int q = (i * 4 + w) * 64 + l;
        qrow[i] = q >> 3;
        qc8[i] = (q & 7) * 8;
    }

    f32x4 acc[4][4] = {};

    for (int k0 = 0; k0 < K; k0 += 64) {
#pragma unroll
        for (int i = 0; i < 4; i++) {
            const unsigned short* sA = A + (rowBase + qrow[i]) * K + k0 + qc8[i];
            const unsigned short* sB = B + (colBase + qrow[i]) * K + k0 + qc8[i];
            __builtin_amdgcn_global_load_lds(
                (const __attribute__((address_space(1))) void*)sA,
                (__attribute__((address_space(3))) void*)(sm + (i * 4 + w) * 512), 16, 0, 0);
            __builtin_amdgcn_global_load_lds(
                (const __attribute__((address_space(1))) void*)sB,
                (__attribute__((address_space(3))) void*)(sm + 8192 + (i * 4 + w) * 512), 16, 0, 0);
        }
        __syncthreads();
#pragma unroll
        for (int ks = 0; ks < 2; ks++) {
            bf16x8 af[4], bfr[4];
#pragma unroll
            for (int mi = 0; mi < 4; mi++)
                af[mi] = *(const bf16x8*)&sm[(wr * 64 + mi * 16 + lr) * 64 + ks * 32 + lq * 8];
#pragma unroll
            for (int ni = 0; ni < 4; ni++)
                bfr[ni] = *(const bf16x8*)&sm[8192 + (wc * 64 + ni * 16 + lr) * 64 + ks * 32 + lq * 8];
#pragma unroll
            for (int mi = 0; mi < 4; mi++)
#pragma unroll
                for (int ni = 0; ni < 4; ni++)
                    acc[mi][ni] = __builtin_amdgcn_mfma_f32_16x16x32_bf16(
                        af[mi], bfr[ni], acc[mi][ni], 0, 0, 0);
        }
        __syncthreads();
    }

    float bv[4];
#pragma unroll
    for (int ni = 0; ni < 4; ni++)
        bv[ni] = bias ? b2f(bias[colBase + wc * 64 + ni * 16 + lr]) : 0.f;

    const bool f32out = (Cf != nullptr) && (*fdt != 0u);
    if (f32out) {
#pragma unroll
        for (int mi = 0; mi < 4; mi++)
#pragma unroll
            for (int ni = 0; ni < 4; ni++)
#pragma unroll
                for (int rg = 0; rg < 4; rg++) {
                    int m = wr * 64 + mi * 16 + lq * 4 + rg;
                    int n = wc * 64 + ni * 16 + lr;
                    Cf[(rowBase + m) * (long)N + colBase + n] = acc[mi][ni][rg] + bv[ni];
                }
        return;
    }

#pragma unroll
    for (int mi = 0; mi < 4; mi++)
#pragma unroll
        for (int ni = 0; ni < 4; ni++)
#pragma unroll
            for (int rg = 0; rg < 4; rg++) {
                int m = wr * 64 + mi * 16 + lq * 4 + rg;
                int n = wc * 64 + ni * 16 + lr;
                sm[m * 128 + n] = f2b(acc[mi][ni][rg] + bv[ni]);
            }
    __syncthreads();
#pragma unroll
    for (int i = 0; i < 8; i++) {
        int idx = i * 2048 + tid * 8;
        int r = idx >> 7, c = idx & 127;
        *(u16x8*)(C + (rowBase + r) * N + colBase + c) = *(const u16x8*)&sm[idx];
    }
}

// Multi-segment GEMM: up to 3 independent GEMMs in ONE dispatch (disjoint
// outputs, inputs all finalized by earlier dispatches -> no coherence issues).
struct GSeg {
    const unsigned short* A;
    const unsigned short* B;
    const unsigned short* bias;
    unsigned short* C;
    float* Cf;
    int M, N, K, tiles, tilesX;
};

__global__ __launch_bounds__(256) void gemm_multi(GSeg s0, GSeg s1, GSeg s2,
                                                  const unsigned* __restrict__ fdt) {
    __shared__ unsigned short sm[16384];
    int b = blockIdx.x;
    const GSeg* s;
    int t;
    if (b < s0.tiles)                 { s = &s0; t = b; }
    else if (b < s0.tiles + s1.tiles) { s = &s1; t = b - s0.tiles; }
    else                              { s = &s2; t = b - s0.tiles - s1.tiles; }
    gemm_tile(s->A, s->B, s->bias, s->C, s->Cf, fdt,
              s->M, s->N, s->K, t % s->tilesX, t / s->tilesX, sm);
}

// ---------------------------------------------------------------------------
// GRU recurrence body — r13 kernel VERBATIM as a device function.
// ---------------------------------------------------------------------------
DEVI void gru_body(
    const unsigned short* __restrict__ gi,   // [Tc][NB][G3]
    const unsigned short* __restrict__ Whh,  // [G3][HD]
    const unsigned short* __restrict__ bhh,  // [G3]
    const float* __restrict__ keep,          // [LSEQ][NB]
    const unsigned short* __restrict__ mem,  // [NB][1024]
    unsigned short* __restrict__ hdb,        // [2][NB][HD]
    unsigned short* __restrict__ Y,          // [Tc][NB][HD]
    unsigned short* __restrict__ hnB, float* __restrict__ hnF,
    bool f32out, int t0, int Tc, int layerOff,
    unsigned* __restrict__ ctr, int lb) {
    const int tid = threadIdx.x;
    const int l = tid & 63, w = tid >> 6, lr = l & 15, lq = l >> 4;
    const int bi = lb & 15, bj = lb >> 4;

    __shared__ float red[4][16][100];  // padded stride

    bf16x8 wreg[6][4];
#pragma unroll
    for (int fr = 0; fr < 6; fr++) {
        int g = fr >> 1, cf = fr & 1;
        long row = (long)g * HD + bj * 32 + cf * 16 + lr;
#pragma unroll
        for (int ks = 0; ks < 4; ks++) {
            int k = w * 128 + ks * 32 + lq * 8;
            wreg[fr][ks] = *(const bf16x8*)(Whh + row * HD + k);
        }
    }

    const int m = tid >> 4, c0 = (tid & 15) * 2;
    const int n_g = bi * 16 + m;
    const int ch = bj * 32 + c0;
    float bh[3][2];
#pragma unroll
    for (int g = 0; g < 3; g++) {
        unsigned v = *(const unsigned*)(bhh + g * HD + ch);
        bh[g][0] = b2f((unsigned short)(v & 0xffffu));
        bh[g][1] = b2f((unsigned short)(v >> 16));
    }

    if (t0 == 0) {  // init h0 from memory (layer slice) into parity 0
        unsigned v = *(const unsigned*)(mem + (long)n_g * 1024 + layerOff + ch);
        cstore((unsigned*)(hdb + (long)n_g * HD + ch), v);
        unsigned* islot = ctr + ((long)Tc * 16 + bi) * 32;
        __syncthreads();
        if (tid == 0) {
            __hip_atomic_fetch_add(islot, 1u, __ATOMIC_RELAXED, __HIP_MEMORY_SCOPE_AGENT);
            while (__hip_atomic_load(islot, __ATOMIC_RELAXED, __HIP_MEMORY_SCOPE_AGENT) < 16u)
                __builtin_amdgcn_s_sleep(1);
        }
        __syncthreads();
    }

    float hpv[2];
    {
        unsigned hp0 = cload((const unsigned*)(hdb + (long)(t0 & 1) * NB * HD + (long)n_g * HD + ch));
        hpv[0] = b2f((unsigned short)(hp0 & 0xffffu));
        hpv[1] = b2f((unsigned short)(hp0 >> 16));
    }

    unsigned gv[3];
    float kp;
    {
        const unsigned short* gp = gi + (long)n_g * G3;
#pragma unroll
        for (int g = 0; g < 3; g++) gv[g] = *(const unsigned*)(gp + g * HD + ch);
        kp = keep[(long)t0 * NB + n_g];
    }

    for (int t = t0; t < t0 + Tc; ++t) {
        const unsigned short* hc = hdb + (long)(t & 1) * NB * HD;
        unsigned short* hx = hdb + (long)((t + 1) & 1) * NB * HD;

        const unsigned* hrow = (const unsigned*)(hc + (long)(bi * 16 + lr) * HD);
        union { u32x4 u; bf16x8 v; } t0u, t1u, t2u, t3u;
        cload4x4(hrow + w * 64 + 0 * 16 + lq * 4, hrow + w * 64 + 1 * 16 + lq * 4,
                 hrow + w * 64 + 2 * 16 + lq * 4, hrow + w * 64 + 3 * 16 + lq * 4,
                 t0u.u, t1u.u, t2u.u, t3u.u);
        bf16x8 af[4] = { t0u.v, t1u.v, t2u.v, t3u.v };

        f32x4 acc[6] = {};
#pragma unroll
        for (int ks = 0; ks < 4; ks++)
#pragma unroll
            for (int fr = 0; fr < 6; fr++)
                acc[fr] = __builtin_amdgcn_mfma_f32_16x16x32_bf16(af[ks], wreg[fr][ks], acc[fr], 0, 0, 0);

#pragma unroll
        for (int fr = 0; fr < 6; fr++)
#pragma unroll
            for (int rg = 0; rg < 4; rg++)
                red[w][lq * 4 + rg][fr * 16 + lr] = acc[fr][rg];
        __syncthreads();

        float s[3][2];
#pragma unroll
        for (int g = 0; g < 3; g++) { s[g][0] = 0.f; s[g][1] = 0.f; }
#pragma unroll
        for (int ww = 0; ww < 4; ww++)
#pragma unroll
            for (int g = 0; g < 3; g++) {
                const float* p = &red[ww][m][g * 32 + c0];
                s[g][0] += p[0];
                s[g][1] += p[1];
            }

        unsigned short yo[2], ho[2];
        float hcf[2];
#pragma unroll
        for (int j = 0; j < 2; j++) {
            float ir  = b2f((unsigned short)((gv[0] >> (16 * j)) & 0xffffu));
            float iz  = b2f((unsigned short)((gv[1] >> (16 * j)) & 0xffffu));
            float in_ = b2f((unsigned short)((gv[2] >> (16 * j)) & 0xffffu));
            float r = 1.f / (1.f + __expf(-(ir + s[0][j] + bh[0][j])));
            float z = 1.f / (1.f + __expf(-(iz + s[1][j] + bh[1][j])));
            float nn = fast_tanh(in_ + r * (s[2][j] + bh[2][j]));
            float hnew = (1.f - z) * nn + z * hpv[j];
            hcf[j] = hnew * kp;
            yo[j] = f2b(hnew);
            ho[j] = f2b(hcf[j]);
            hpv[j] = b2f(ho[j]);
        }
        unsigned ypack = (unsigned)yo[0] | ((unsigned)yo[1] << 16);
        unsigned hpack = (unsigned)ho[0] | ((unsigned)ho[1] << 16);

        cstore((unsigned*)(hx + (long)n_g * HD + ch), hpack);  // barrier-gated

        const bool last = (t + 1 >= t0 + Tc);
        unsigned* slot = ctr + ((long)(t - t0) * 16 + bi) * 32;
        if (!last) {
            __syncthreads();  // drains the h cstore
            if (tid == 0)
                __hip_atomic_fetch_add(slot, 1u, __ATOMIC_RELAXED, __HIP_MEMORY_SCOPE_AGENT);
        }

        *(unsigned*)(Y + ((long)(t - t0) * NB + n_g) * HD + ch) = ypack;
        if (t == LSEQ - 1) {
            if (f32out) {
                hnF[(long)n_g * 1024 + layerOff + ch]     = hcf[0];
                hnF[(long)n_g * 1024 + layerOff + ch + 1] = hcf[1];
            } else {
                *(unsigned*)(hnB + (long)n_g * 1024 + layerOff + ch) = hpack;
            }
        }
        if (!last) {
            const unsigned short* gp = gi + ((long)(t + 1 - t0) * NB + n_g) * G3;
#pragma unroll
            for (int g = 0; g < 3; g++) gv[g] = *(const unsigned*)(gp + g * HD + ch);
            kp = keep[(long)(t + 1) * NB + n_g];
            if (tid == 0) {
                while (__hip_atomic_load(slot, __ATOMIC_RELAXED, __HIP_MEMORY_SCOPE_AGENT) < 16u)
                    __builtin_amdgcn_s_sleep(1);
            }
            __syncthreads();
        }
    }
}

// ---------------------------------------------------------------------------
// Dual-layer dispatch: blocks 0-255 = L0 chunk c, blocks 256-511 = L1 chunk
// c-1. Fully independent halves; 2 blocks/CU co-resident.
// ---------------------------------------------------------------------------
__global__ __launch_bounds__(256, 2) void gru_dual(
    const unsigned short* giA, const unsigned short* WhhA, const unsigned short* bhhA,
    unsigned short* hdbA, unsigned short* YA, int t0A, unsigned* ctrA, int enA,
    const unsigned short* giB, const unsigned short* WhhB, const unsigned short* bhhB,
    unsigned short* hdbB, unsigned short* YB, int t0B, unsigned* ctrB, int enB,
    const float* keep, const unsigned short* mem,
    unsigned short* hnB, float* hnF, const unsigned* fdt, int Tc) {
    const bool f32out = (*fdt != 0u);
    const int half = blockIdx.x >> 8;
    const int lb = blockIdx.x & 255;
    if (half == 0) {
        if (enA) gru_body(giA, WhhA, bhhA, keep, mem, hdbA, YA, hnB, hnF,
                          f32out, t0A, Tc, 0, ctrA, lb);
    } else {
        if (enB) gru_body(giB, WhhB, bhhB, keep, mem, hdbB, YB, hnB, hnF,
                          f32out, t0B, Tc, HD, ctrB, lb);
    }
}

// ---------------------------------------------------------------------------
// Host launcher — layer-pipelined duals + consolidated multi-GEMM.
// ---------------------------------------------------------------------------
extern "C" void kernel_launch(void* const* d_in, const int* in_sizes, int n_in,
                              void* d_out, int out_size, void* d_ws, size_t ws_size,
                              hipStream_t stream) {
    const void* x    = d_in[0];
    const void* mem  = d_in[1];
    const void* done = d_in[2];
    const void* fsrc[11] = { mem, d_in[3], d_in[4], d_in[5], d_in[6],
                             d_in[7], d_in[8], d_in[9], d_in[10], d_in[11], d_in[12] };
    const long  fn[11]   = { (long)NB * 1024, (long)G3 * CIN, (long)G3 * HD, G3, G3,
                             (long)G3 * HD, (long)G3 * HD, G3, G3, (long)NOUT * HD, NOUT };

    unsigned short* outB = (unsigned short*)d_out;
    float*          outF = (float*)d_out;
    unsigned short* hnB  = outB + (size_t)LSEQ * NB * NOUT;
    float*          hnF  = outF + (size_t)LSEQ * NB * NOUT;

    char* ws = (char*)d_ws;
    const size_t oFlag = 0;                                   // fdt @ +0, done-flag @ +64
    const size_t oKeep = 256;
    const size_t oCtr  = oKeep + (size_t)LSEQ * NB * 4;       // 8 MB barrier slots
    const size_t oWC   = oCtr + (size_t)8 * 1024 * 1024;      // staged weights/mem
    size_t wcTot = 0;
    size_t wcOff[11];
    for (int i = 0; i < 11; i++) { wcOff[i] = wcTot; wcTot += (size_t)fn[i] * 2; wcTot = (wcTot + 255) & ~(size_t)255; }
    const size_t oHdb0 = oWC + wcTot;
    const size_t oHdb1 = oHdb0 + (size_t)2 * NB * HD * 2;
    const size_t oDyn  = oHdb1 + (size_t)2 * NB * HD * 2;

    int Tc = 4;
    const int cand[6] = {128, 64, 32, 16, 8, 4};
    for (int i = 0; i < 6; i++) {
        size_t need = oDyn + (size_t)cand[i] * NB * (CIN + 2 * G3 + 2 * HD) * 2;
        if (need <= ws_size) { Tc = cand[i]; break; }
    }
    const size_t oXC  = oDyn;
    const size_t oGI0 = oXC + (size_t)Tc * NB * CIN * 2;
    const size_t oGI1 = oGI0 + (size_t)Tc * NB * G3 * 2;
    const size_t oY0c = oGI1 + (size_t)Tc * NB * G3 * 2;
    const size_t oY1c = oY0c + (size_t)Tc * NB * HD * 2;

    unsigned*       FDT  = (unsigned*)(ws + oFlag);
    unsigned*       DFLG = (unsigned*)(ws + oFlag + 64);
    float*          KEEP = (float*)(ws + oKeep);
    unsigned*       CTR  = (unsigned*)(ws + oCtr);
    unsigned short* WC   = (unsigned short*)(ws + oWC);
    unsigned short* HDB0 = (unsigned short*)(ws + oHdb0);
    unsigned short* HDB1 = (unsigned short*)(ws + oHdb1);
    unsigned short* XC   = (unsigned short*)(ws + oXC);
    unsigned short* GI0  = (unsigned short*)(ws + oGI0);
    unsigned short* GI1  = (unsigned short*)(ws + oGI1);
    unsigned short* Y0c  = (unsigned short*)(ws + oY0c);
    unsigned short* Y1c  = (unsigned short*)(ws + oY1c);

    unsigned short* MEMc = WC + wcOff[0] / 2;
    unsigned short* WIH0 = WC + wcOff[1] / 2;
    unsigned short* WHH0 = WC + wcOff[2] / 2;
    unsigned short* BIH0 = WC + wcOff[3] / 2;
    unsigned short* BHH0 = WC + wcOff[4] / 2;
    unsigned short* WIH1 = WC + wcOff[5] / 2;
    unsigned short* WHH1 = WC + wcOff[6] / 2;
    unsigned short* BIH1 = WC + wcOff[7] / 2;
    unsigned short* BHH1 = WC + wcOff[8] / 2;
    unsigned short* WPc  = WC + wcOff[9] / 2;
    unsigned short* BPc  = WC + wcOff[10] / 2;

    hipMemsetAsync(ws + oCtr, 0, (size_t)8 * 1024 * 1024, stream);
    detect_fdt<<<1, 256, 0, stream>>>((const unsigned short*)x, 4096, FDT);
    detect_done<<<1, 256, 0, stream>>>((const unsigned char*)done, in_sizes[2], DFLG);
    expand_done<<<(LSEQ * NB + 255) / 256, 256, 0, stream>>>(done, DFLG, KEEP, LSEQ * NB);

    for (int i = 0; i < 11; i++) {
        int blocks = (int)((fn[i] + 1023) / 1024);
        if (blocks > 2048) blocks = 2048;
        cast_bf16<<<blocks, 256, 0, stream>>>(fsrc[i], 0, WC + wcOff[i] / 2, fn[i], FDT);
    }

    const int NC = LSEQ / Tc;
    const size_t SZ = (size_t)(Tc + 2) * 16 * 32;  // ctr region dwords per instance
    const long giN = (long)Tc * NB * CIN;
    const int MT = Tc * NB / 128;                  // M-tiles per chunk GEMM
    const GSeg ZSEG = { nullptr, nullptr, nullptr, nullptr, nullptr, 0, 0, 0, 0, 1 };

    // prologue: GI0 for chunk 0
    cast_bf16<<<2048, 256, 0, stream>>>(x, 0, XC, giN, FDT);
    {
        GSeg s0 = ZSEG, s1 = ZSEG;
        GSeg s2 = { XC, WIH0, BIH0, GI0, nullptr, Tc * NB, G3, CIN, MT * (G3 / 128), G3 / 128 };
        gemm_multi<<<s2.tiles, 256, 0, stream>>>(s0, s1, s2, FDT);
    }

    for (int it = 0; it <= NC; ++it) {
        const int cA = it, cB = it - 1;
        const int enA = (cA < NC) ? 1 : 0;
        const int enB = (cB >= 0) ? 1 : 0;

        gru_dual<<<512, 256, 0, stream>>>(
            GI0, WHH0, BHH0, HDB0, Y0c, cA * Tc, CTR + (size_t)(2 * it) * SZ, enA,
            GI1, WHH1, BHH1, HDB1, Y1c, cB * Tc, CTR + (size_t)(2 * it + 1) * SZ, enB,
            KEEP, MEMc, hnB, hnF, FDT, Tc);

        // consolidated GEMMs: gemm1(cA) + proj(cB) + gemm0(cA+1), one dispatch
        const int doG0 = (cA + 1 < NC) ? 1 : 0;
        if (doG0)
            cast_bf16<<<2048, 256, 0, stream>>>(x, (long)(cA + 1) * Tc * NB * CIN, XC, giN, FDT);

        GSeg s0 = ZSEG, s1 = ZSEG, s2 = ZSEG;
        if (enA)
            s0 = GSeg{ Y0c, WIH1, BIH1, GI1, nullptr, Tc * NB, G3, HD, MT * (G3 / 128), G3 / 128 };
        if (enB)
            s1 = GSeg{ Y1c, WPc, BPc, outB + (size_t)cB * Tc * NB * NOUT,
                       outF + (size_t)cB * Tc * NB * NOUT, Tc * NB, NOUT, HD,
                       MT * (NOUT / 128), NOUT / 128 };
        if (doG0)
            s2 = GSeg{ XC, WIH0, BIH0, GI0, nullptr, Tc * NB, G3, CIN, MT * (G3 / 128), G3 / 128 };
        const int total = s0.tiles + s1.tiles + s2.tiles;
        if (total)
            gemm_multi<<<total, 256, 0, stream>>>(s0, s1, s2, FDT);
    }
}